// Round 1
// baseline (116.553 us; speedup 1.0000x reference)
//
#include <hip/hip_runtime.h>
#include <stdint.h>

using bf16x8_t = __attribute__((ext_vector_type(8))) __bf16;
using f32x4_t  = __attribute__((ext_vector_type(4))) float;
using u16x4_t  = __attribute__((ext_vector_type(4))) unsigned short;
using u16x8_t  = __attribute__((ext_vector_type(8))) unsigned short;

#define KD 2048   // hidden dim

static __device__ __forceinline__ unsigned short f2bf(float f) {
  union { float f; unsigned u; } v; v.f = f;
  unsigned r = v.u + 0x7fffu + ((v.u >> 16) & 1u);   // RNE
  return (unsigned short)(r >> 16);
}

// wsum[h] = sum_d w_qkv[d,h] + sum_d w_z[d,h]   (folds qkv.sum + z.sum into one dot)
__global__ void k_wsum(const float* __restrict__ wqkv, const float* __restrict__ wz,
                       float* __restrict__ wsum) {
  int h = blockIdx.x * 256 + threadIdx.x;       // 2048 threads
  float s = 0.f;
  for (int d = 0; d < 768; ++d) s += wqkv[d * KD + h];
  for (int d = 0; d < 512; ++d) s += wz[d * KD + h];
  wsum[h] = s;
}

// pack bf16 weight matrix: rows 0..63 = w_a, rows 64..127 = w_b, row-major [128][2048]
__global__ void k_pack(const float* __restrict__ wa, const float* __restrict__ wb,
                       unsigned short* __restrict__ wbf) {
  int idx = blockIdx.x * 256 + threadIdx.x;     // 32768 threads, 8 elems each
  int n = idx >> 8;
  int kc = (idx & 255) * 8;
  const float* src = (n < 64) ? (wa + n * KD + kc) : (wb + (n - 64) * KD + kc);
  f32x4_t v0 = *(const f32x4_t*)(src);
  f32x4_t v1 = *(const f32x4_t*)(src + 4);
  u16x8_t o;
  o[0] = f2bf(v0[0]); o[1] = f2bf(v0[1]); o[2] = f2bf(v0[2]); o[3] = f2bf(v0[3]);
  o[4] = f2bf(v1[0]); o[5] = f2bf(v1[1]); o[6] = f2bf(v1[2]); o[7] = f2bf(v1[3]);
  *(u16x8_t*)(wbf + n * KD + kc) = o;
}

// Main: BM=64 tokens/block, K-step 64, N=128 (64 a-cols | 64 b-cols).
// 4 waves; wave w computes rows [w*16, w*16+16) x all 128 cols via mfma_f32_16x16x32_bf16.
// s0 = fp32 dot(x, wsum) computed during staging.
__global__ __launch_bounds__(256, 4) void k_main(
    const float* __restrict__ x, const float* __restrict__ wsum,
    const unsigned short* __restrict__ wbf, float* __restrict__ out)
{
  __shared__ __align__(16) unsigned char lds[8192 + 16384 + 256];
  unsigned char* xs  = lds;           // X tile  [64 rows][64 k] bf16, swizzled
  unsigned char* wsb = lds + 8192;    // W tile  [128 rows][64 k] bf16, swizzled
  float* s0buf = (float*)(lds + 24576);

  const int t    = threadIdx.x;
  const int lane = t & 63;
  const int wv   = t >> 6;
  const size_t tile = (size_t)blockIdx.x * 64;

  // X staging map: 16 float4-chunks per row, 4 rows per thread
  const int kq = t & 15;
  const int r0 = t >> 4;
  // W staging map: 8 16B-chunks per row, 4 rows per thread
  const int wq8 = t & 7;
  const int wn0 = t >> 3;

  f32x4_t acc[8];
  #pragma unroll
  for (int i = 0; i < 8; ++i) acc[i] = f32x4_t{0.f, 0.f, 0.f, 0.f};
  float s0p[4] = {0.f, 0.f, 0.f, 0.f};

  // fragment addressing (verified layouts: A row=lane&15,k=(lane>>4)*8+j ;
  // B col=lane&15,k=(lane>>4)*8+j ; C col=lane&15,row=(lane>>4)*4+reg)
  const int arow = wv * 16 + (lane & 15);
  const int abase = arow * 128;
  const int asw = (arow & 7) << 4;
  const int kofs = (lane >> 4) * 16;       // byte offset of this lane's k-group
  const int bcol = lane & 15;
  const int bbase = bcol * 128;
  const int bsw = (bcol & 7) << 4;

  for (int ks = 0; ks < 32; ++ks) {
    const int kk = ks * 64;

    // ---- global loads into regs (overlap with other waves' compute) ----
    f32x4_t xv[4];
    #pragma unroll
    for (int i = 0; i < 4; ++i)
      xv[i] = *(const f32x4_t*)(x + (tile + (size_t)(r0 + 16 * i)) * KD + kk + kq * 4);
    f32x4_t wqv = *(const f32x4_t*)(wsum + kk + kq * 4);
    u16x8_t wld[4];
    #pragma unroll
    for (int i = 0; i < 4; ++i)
      wld[i] = *(const u16x8_t*)(wbf + (wn0 + 32 * i) * KD + kk + wq8 * 8);

    __syncthreads();   // previous compute done, LDS reusable

    // ---- stage X (f32 -> bf16) with XOR swizzle; accumulate fp32 s0 ----
    #pragma unroll
    for (int i = 0; i < 4; ++i) {
      int row = r0 + 16 * i;
      u16x4_t h;
      h[0] = f2bf(xv[i][0]); h[1] = f2bf(xv[i][1]);
      h[2] = f2bf(xv[i][2]); h[3] = f2bf(xv[i][3]);
      *(u16x4_t*)(xs + row * 128 + ((kq * 8) ^ ((row & 7) << 4))) = h;
      s0p[i] += xv[i][0] * wqv[0] + xv[i][1] * wqv[1] +
                xv[i][2] * wqv[2] + xv[i][3] * wqv[3];
    }
    // ---- stage W with same swizzle ----
    #pragma unroll
    for (int i = 0; i < 4; ++i) {
      int n = wn0 + 32 * i;
      *(u16x8_t*)(wsb + n * 128 + ((wq8 * 16) ^ ((n & 7) << 4))) = wld[i];
    }

    __syncthreads();   // tiles visible

    // ---- 16 MFMA: 2 k-halves x 8 col-frags ----
    #pragma unroll
    for (int kh = 0; kh < 2; ++kh) {
      bf16x8_t af = *(const bf16x8_t*)(xs + abase + ((kofs + kh * 64) ^ asw));
      #pragma unroll
      for (int nf = 0; nf < 8; ++nf) {
        bf16x8_t bfr = *(const bf16x8_t*)(wsb + nf * 2048 + bbase + ((kofs + kh * 64) ^ bsw));
        acc[nf] = __builtin_amdgcn_mfma_f32_16x16x32_bf16(af, bfr, acc[nf], 0, 0, 0);
      }
    }
  }

  // ---- s0 reduction: 16 threads (kq) share each row ----
  #pragma unroll
  for (int i = 0; i < 4; ++i) {
    float v = s0p[i];
    v += __shfl_xor(v, 1, 64);
    v += __shfl_xor(v, 2, 64);
    v += __shfl_xor(v, 4, 64);
    v += __shfl_xor(v, 8, 64);
    if ((lane & 15) == 0) s0buf[r0 + 16 * i] = v;
  }
  __syncthreads();

  // ---- epilogue: pair a-col j (frag nf) with b-col 64+j (frag nf+4), same lane/reg ----
  const int g = lane >> 4;
  #pragma unroll
  for (int r = 0; r < 4; ++r) {
    float v = 0.f;
    #pragma unroll
    for (int nf = 0; nf < 4; ++nf) {
      float av = acc[nf][r];
      float bv = acc[nf + 4][r];
      v += av / (1.f + __expf(-bv));     // a * sigmoid(b)
    }
    v += __shfl_xor(v, 1, 64);
    v += __shfl_xor(v, 2, 64);
    v += __shfl_xor(v, 4, 64);
    v += __shfl_xor(v, 8, 64);
    if ((lane & 15) == 0) {
      int row = g * 4 + r;               // C row = (lane>>4)*4 + reg
      out[tile + wv * 16 + row] = v + s0buf[wv * 16 + row];
    }
  }
}

extern "C" void kernel_launch(void* const* d_in, const int* in_sizes, int n_in,
                              void* d_out, int out_size, void* d_ws, size_t ws_size,
                              hipStream_t stream) {
  const float* x    = (const float*)d_in[0];
  const float* wqkv = (const float*)d_in[1];
  const float* wz   = (const float*)d_in[2];
  const float* wb   = (const float*)d_in[3];   // note dict order: w_b before w_a
  const float* wa   = (const float*)d_in[4];
  float* out = (float*)d_out;

  float* wsum = (float*)d_ws;                                   // 2048 f32  (8 KB)
  unsigned short* wbf = (unsigned short*)((char*)d_ws + 8192);  // 128x2048 bf16 (512 KB)

  k_wsum<<<8, 256, 0, stream>>>(wqkv, wz, wsum);
  k_pack<<<128, 256, 0, stream>>>(wa, wb, wbf);
  k_main<<<out_size / 64, 256, 0, stream>>>(x, wsum, wbf, out);
}